// Round 1
// baseline (701.953 us; speedup 1.0000x reference)
//
#include <hip/hip_runtime.h>
#include <math.h>

#define NN 50000
#define NE 800000
#define EMB 128
#define GH 64
#define BB 64
#define TT 200
#define HH 128
#define G4 512
#define IND 134

__device__ __forceinline__ float sigf(float x) { return 1.0f / (1.0f + __expf(-x)); }
__device__ __forceinline__ float tanhf_(float x) { return 1.0f - 2.0f / (__expf(2.0f * x) + 1.0f); }
__device__ __forceinline__ void fma4(float4& a, float s, const float4 w) {
    a.x += s * w.x; a.y += s * w.y; a.z += s * w.z; a.w += s * w.w;
}

// ---------------- CSR build ----------------
__global__ void hist_kernel(const int* __restrict__ ei, const float* __restrict__ ew,
                            int* __restrict__ cnt, float* __restrict__ degw) {
    int e = blockIdx.x * 256 + threadIdx.x;
    if (e >= NE) return;
    int d = ei[NE + e];
    atomicAdd(&cnt[d], 1);
    atomicAdd(&degw[d], ew[e]);
}

__global__ void dinv_kernel(const float* __restrict__ degw, float* __restrict__ dinv) {
    int n = blockIdx.x * 256 + threadIdx.x;
    if (n >= NN) return;
    dinv[n] = rsqrtf(degw[n] + 1.0f);   // +1 self loop
}

__global__ __launch_bounds__(1024) void scan1_kernel(const int* __restrict__ cnt,
                                                     int* __restrict__ rs, int* __restrict__ partials) {
    __shared__ int s[1024];
    int gid = blockIdx.x * 1024 + threadIdx.x;
    int v = (gid < NN) ? cnt[gid] : 0;
    s[threadIdx.x] = v;
    __syncthreads();
    for (int off = 1; off < 1024; off <<= 1) {
        int add = (threadIdx.x >= (unsigned)off) ? s[threadIdx.x - off] : 0;
        __syncthreads();
        s[threadIdx.x] += add;
        __syncthreads();
    }
    if (gid < NN) rs[gid] = s[threadIdx.x] - v;  // exclusive
    if (threadIdx.x == 1023) partials[blockIdx.x] = s[1023];
}

__global__ void scan2_kernel(int* __restrict__ partials, int nblk) {
    if (threadIdx.x == 0) {
        int acc = 0;
        for (int i = 0; i < nblk; ++i) { int v = partials[i]; partials[i] = acc; acc += v; }
    }
}

__global__ __launch_bounds__(1024) void scan3_kernel(const int* __restrict__ partials,
                                                     int* __restrict__ rs, int* __restrict__ cursor) {
    int gid = blockIdx.x * 1024 + threadIdx.x;
    if (gid < NN) {
        int v = rs[gid] + partials[gid >> 10];
        rs[gid] = v;
        cursor[gid] = v;
    }
    if (gid == 0) rs[NN] = NE;
}

__global__ void fill_kernel(const int* __restrict__ ei, const float* __restrict__ ew,
                            const float* __restrict__ dinv, int* __restrict__ cursor,
                            int* __restrict__ ssrc, float* __restrict__ sw) {
    int e = blockIdx.x * 256 + threadIdx.x;
    if (e >= NE) return;
    int s = ei[e], d = ei[NE + e];
    int pos = atomicAdd(&cursor[d], 1);
    ssrc[pos] = s;
    sw[pos] = ew[e] * dinv[s] * dinv[d];
}

// ---------------- GCN layer 1 GEMM (fused concat, 134 -> 64) ----------------
__global__ __launch_bounds__(256) void gemm1_kernel(const float* __restrict__ coords,
                                                    const float* __restrict__ temporal,
                                                    const float* __restrict__ emb,
                                                    const float* __restrict__ W1,
                                                    float* __restrict__ h1) {
    __shared__ __align__(16) float wl[IND][GH];
    for (int i = threadIdx.x; i < IND * GH / 4; i += 256)
        ((float4*)wl)[i] = ((const float4*)W1)[i];
    __syncthreads();
    int n = blockIdx.x * 256 + threadIdx.x;
    if (n >= NN) return;
    float4 acc[16];
    float c0 = coords[2 * n], c1 = coords[2 * n + 1];
#pragma unroll
    for (int j = 0; j < 16; ++j) {
        float4 wa = *(const float4*)&wl[0][j * 4];
        float4 wb = *(const float4*)&wl[1][j * 4];
        float4 a;
        a.x = c0 * wa.x + c1 * wb.x; a.y = c0 * wa.y + c1 * wb.y;
        a.z = c0 * wa.z + c1 * wb.z; a.w = c0 * wa.w + c1 * wb.w;
        acc[j] = a;
    }
    const float4* er = (const float4*)(emb + (size_t)n * EMB);
#pragma unroll 2
    for (int k4 = 0; k4 < 32; ++k4) {
        float4 v = er[k4];
        int k = 2 + k4 * 4;
#pragma unroll
        for (int j = 0; j < 16; ++j) {
            fma4(acc[j], v.x, *(const float4*)&wl[k][j * 4]);
            fma4(acc[j], v.y, *(const float4*)&wl[k + 1][j * 4]);
            fma4(acc[j], v.z, *(const float4*)&wl[k + 2][j * 4]);
            fma4(acc[j], v.w, *(const float4*)&wl[k + 3][j * 4]);
        }
    }
    float t0 = temporal[4 * n], t1 = temporal[4 * n + 1], t2 = temporal[4 * n + 2], t3 = temporal[4 * n + 3];
#pragma unroll
    for (int j = 0; j < 16; ++j) {
        fma4(acc[j], t0, *(const float4*)&wl[130][j * 4]);
        fma4(acc[j], t1, *(const float4*)&wl[131][j * 4]);
        fma4(acc[j], t2, *(const float4*)&wl[132][j * 4]);
        fma4(acc[j], t3, *(const float4*)&wl[133][j * 4]);
        *(float4*)&h1[(size_t)n * GH + j * 4] = acc[j];
    }
}

// ---------------- symmetric-norm aggregation (64 features, CSR) ----------------
__global__ __launch_bounds__(256) void agg_kernel(const float* __restrict__ hin,
                                                  const int* __restrict__ rs,
                                                  const int* __restrict__ ssrc,
                                                  const float* __restrict__ sw,
                                                  const float* __restrict__ dinv,
                                                  const float* __restrict__ bias, int relu,
                                                  float* __restrict__ hout) {
    int lane = threadIdx.x & 63;
    int wid = threadIdx.x >> 6;
    int n = blockIdx.x * 4 + wid;
    if (n >= NN) return;
    float dv = dinv[n];
    float acc = hin[(size_t)n * GH + lane] * (dv * dv);  // self loop
    int i = rs[n], e1 = rs[n + 1];
    for (; i + 3 < e1; i += 4) {
        int s0 = ssrc[i], s1 = ssrc[i + 1], s2 = ssrc[i + 2], s3 = ssrc[i + 3];
        float w0 = sw[i], w1 = sw[i + 1], w2 = sw[i + 2], w3 = sw[i + 3];
        float a0 = hin[(size_t)s0 * GH + lane];
        float a1 = hin[(size_t)s1 * GH + lane];
        float a2 = hin[(size_t)s2 * GH + lane];
        float a3 = hin[(size_t)s3 * GH + lane];
        acc += a0 * w0 + a1 * w1 + a2 * w2 + a3 * w3;
    }
    for (; i < e1; ++i) acc += hin[(size_t)ssrc[i] * GH + lane] * sw[i];
    if (bias) acc += bias[lane];
    if (relu) acc = fmaxf(acc, 0.0f);
    hout[(size_t)n * GH + lane] = acc;
}

// ---------------- GCN layer 2 GEMM (64 -> 128) + bias ----------------
__global__ __launch_bounds__(256) void gemm2_kernel(const float* __restrict__ a2,
                                                    const float* __restrict__ W2,
                                                    const float* __restrict__ b2,
                                                    float* __restrict__ z2) {
    __shared__ __align__(16) float wl[GH][64];
    int j0 = blockIdx.y * 64;
    for (int i = threadIdx.x; i < GH * 16; i += 256) {
        int k = i >> 4, j4 = i & 15;
        *(float4*)&wl[k][j4 * 4] = *(const float4*)&W2[(size_t)k * EMB + j0 + j4 * 4];
    }
    __syncthreads();
    int n = blockIdx.x * 256 + threadIdx.x;
    if (n >= NN) return;
    float4 acc[16];
#pragma unroll
    for (int j = 0; j < 16; ++j) acc[j] = *(const float4*)&b2[j0 + j * 4];
    const float4* ar = (const float4*)(a2 + (size_t)n * GH);
#pragma unroll 2
    for (int k4 = 0; k4 < 16; ++k4) {
        float4 v = ar[k4];
        int k = k4 * 4;
#pragma unroll
        for (int j = 0; j < 16; ++j) {
            fma4(acc[j], v.x, *(const float4*)&wl[k][j * 4]);
            fma4(acc[j], v.y, *(const float4*)&wl[k + 1][j * 4]);
            fma4(acc[j], v.z, *(const float4*)&wl[k + 2][j * 4]);
            fma4(acc[j], v.w, *(const float4*)&wl[k + 3][j * 4]);
        }
    }
#pragma unroll
    for (int j = 0; j < 16; ++j)
        *(float4*)&z2[(size_t)n * EMB + j0 + j * 4] = acc[j];
}

// ---------------- gather sequence embeddings ----------------
__global__ void gather_kernel(const int* __restrict__ seq, const float* __restrict__ z2,
                              float* __restrict__ se) {
    int idx = blockIdx.x * 256 + threadIdx.x;
    if (idx >= BB * TT * 32) return;
    int r = idx >> 5, q = idx & 31;
    int node = seq[r];
    ((float4*)se)[(size_t)r * 32 + q] = ((const float4*)z2)[(size_t)node * 32 + q];
}

// ---------------- pre-GEMM: x @ w_ih.T + biases, layout [T][B][512] ----------------
__global__ __launch_bounds__(256) void pregemm_kernel(const float* __restrict__ se,
                                                      const float* __restrict__ w_ih_f,
                                                      const float* __restrict__ w_ih_b,
                                                      const float* __restrict__ b_ih_f,
                                                      const float* __restrict__ b_hh_f,
                                                      const float* __restrict__ b_ih_b,
                                                      const float* __restrict__ b_hh_b,
                                                      const int* __restrict__ lengths,
                                                      float* __restrict__ xpf,
                                                      float* __restrict__ xpb) {
    int dir = blockIdx.z;
    const float* w_ih = dir ? w_ih_b : w_ih_f;
    int u0 = blockIdx.y * 64;
    __shared__ __align__(16) float wl[64][EMB];
    __shared__ float bs[64];
    {
        const float4* src = (const float4*)(w_ih + (size_t)u0 * EMB);
        for (int i = threadIdx.x; i < 64 * EMB / 4; i += 256) ((float4*)wl)[i] = src[i];
        if (threadIdx.x < 64) {
            int u = u0 + threadIdx.x;
            bs[threadIdx.x] = dir ? (b_ih_b[u] + b_hh_b[u]) : (b_ih_f[u] + b_hh_f[u]);
        }
    }
    __syncthreads();
    int m = blockIdx.x * 256 + threadIdx.x;  // m = t*64 + b
    if (m >= TT * BB) return;
    int t = m >> 6, b = m & 63;
    int tsrc = t;
    if (dir) {
        int len = lengths[b];
        if (t >= len) return;
        tsrc = len - 1 - t;
    }
    const float4* row = (const float4*)(se + ((size_t)b * TT + tsrc) * EMB);
    float accs[64];
#pragma unroll
    for (int j = 0; j < 64; ++j) accs[j] = bs[j];
#pragma unroll 2
    for (int k4 = 0; k4 < 32; ++k4) {
        float4 xv = row[k4];
#pragma unroll
        for (int j = 0; j < 64; ++j) {
            float4 wv = *(const float4*)&wl[j][k4 * 4];
            accs[j] += xv.x * wv.x + xv.y * wv.y + xv.z * wv.z + xv.w * wv.w;
        }
    }
    float* xp = dir ? xpb : xpf;
#pragma unroll
    for (int j4 = 0; j4 < 16; ++j4) {
        float4 o = make_float4(accs[j4 * 4], accs[j4 * 4 + 1], accs[j4 * 4 + 2], accs[j4 * 4 + 3]);
        *(float4*)&xp[(size_t)m * G4 + u0 + j4 * 4] = o;
    }
}

// ---------------- LSTM recurrence: 128 chains, weights in registers ----------------
__global__ __launch_bounds__(512) void lstm_kernel(const float* __restrict__ xpf,
                                                   const float* __restrict__ xpb,
                                                   const float* __restrict__ w_hh_f,
                                                   const float* __restrict__ w_hh_b,
                                                   const int* __restrict__ lengths,
                                                   float* __restrict__ hfo,
                                                   float* __restrict__ hbo) {
    int chain = blockIdx.x;
    int dir = chain & 1, b = chain >> 1;
    const float* w_hh = dir ? w_hh_b : w_hh_f;
    const float* xp = dir ? xpb : xpf;
    float* ho = dir ? hbo : hfo;
    int u = threadIdx.x;
    int len = lengths[b];
    float w[HH];
    {
        const float4* wr = (const float4*)(w_hh + (size_t)u * HH);
#pragma unroll
        for (int k4 = 0; k4 < 32; ++k4) {
            float4 v = wr[k4];
            w[k4 * 4] = v.x; w[k4 * 4 + 1] = v.y; w[k4 * 4 + 2] = v.z; w[k4 * 4 + 3] = v.w;
        }
    }
    __shared__ __align__(16) float hl[HH];
    __shared__ float gl[G4];
    float c = 0.0f;
    if (u < HH) hl[u] = 0.0f;
    __syncthreads();
    for (int t = 0; t < len; ++t) {
        float acc = xp[((size_t)t * BB + b) * G4 + u];
#pragma unroll
        for (int k4 = 0; k4 < 32; ++k4) {
            float4 hv = *(const float4*)&hl[k4 * 4];
            acc += w[k4 * 4] * hv.x + w[k4 * 4 + 1] * hv.y + w[k4 * 4 + 2] * hv.z + w[k4 * 4 + 3] * hv.w;
        }
        gl[u] = acc;
        __syncthreads();
        if (u < HH) {
            float gi = sigf(gl[u]);
            float gf = sigf(gl[HH + u]);
            float gg = tanhf_(gl[2 * HH + u]);
            float go = sigf(gl[3 * HH + u]);
            c = gf * c + gi * gg;
            float h = go * tanhf_(c);
            int tt = dir ? (len - 1 - t) : t;
            ho[((size_t)b * TT + tt) * HH + u] = h;
            hl[u] = h;
        }
        __syncthreads();
    }
}

// ---------------- masked attention pooling ----------------
__global__ __launch_bounds__(256) void attn_kernel(const float* __restrict__ hf,
                                                   const float* __restrict__ hb,
                                                   const float* __restrict__ attn_w,
                                                   const float* __restrict__ attn_b,
                                                   const int* __restrict__ lengths,
                                                   float* __restrict__ ctx) {
    int b = blockIdx.x;
    int tid = threadIdx.x;
    int len = lengths[b];
    __shared__ __align__(16) float wl[256];
    __shared__ float pl[256];
    __shared__ float red[256];
    wl[tid] = attn_w[tid];
    __syncthreads();
    float sc = -3.0e38f;
    if (tid < len) {
        const float4* rf = (const float4*)(hf + ((size_t)b * TT + tid) * HH);
        const float4* rb = (const float4*)(hb + ((size_t)b * TT + tid) * HH);
        const float4* w4 = (const float4*)wl;
        float s = attn_b[0];
        for (int k4 = 0; k4 < 32; ++k4) {
            float4 a = rf[k4], ww = w4[k4];
            s += a.x * ww.x + a.y * ww.y + a.z * ww.z + a.w * ww.w;
        }
        for (int k4 = 0; k4 < 32; ++k4) {
            float4 a = rb[k4], ww = w4[32 + k4];
            s += a.x * ww.x + a.y * ww.y + a.z * ww.z + a.w * ww.w;
        }
        sc = s;
    }
    red[tid] = sc;
    __syncthreads();
    for (int off = 128; off > 0; off >>= 1) {
        if (tid < off) red[tid] = fmaxf(red[tid], red[tid + off]);
        __syncthreads();
    }
    float mx = red[0];
    __syncthreads();
    float e = (tid < len) ? __expf(sc - mx) : 0.0f;
    red[tid] = e;
    __syncthreads();
    for (int off = 128; off > 0; off >>= 1) {
        if (tid < off) red[tid] += red[tid + off];
        __syncthreads();
    }
    float inv = 1.0f / red[0];
    pl[tid] = e * inv;
    __syncthreads();
    float acc = 0.0f;
    const float* basep = (tid < HH) ? (hf + (size_t)b * TT * HH + tid)
                                    : (hb + (size_t)b * TT * HH + (tid - HH));
    for (int t = 0; t < len; ++t) acc += pl[t] * basep[(size_t)t * HH];
    ctx[(size_t)b * 256 + tid] = acc;
}

// ---------------- final FC: [64,256] @ [256,N] + b ----------------
__global__ __launch_bounds__(256) void fc_kernel(const float* __restrict__ ctx,
                                                 const float* __restrict__ fc_w,
                                                 const float* __restrict__ fc_b,
                                                 float* __restrict__ out) {
    __shared__ __align__(16) float cl[64][256];
    for (int i = threadIdx.x; i < 64 * 256 / 4; i += 256)
        ((float4*)cl)[i] = ((const float4*)ctx)[i];
    __syncthreads();
    int nb = threadIdx.x & 63;
    int bq = threadIdx.x >> 6;
    int n = blockIdx.x * 64 + nb;
    if (n >= NN) return;
    float acc[16];
#pragma unroll
    for (int i = 0; i < 16; ++i) acc[i] = 0.0f;
#pragma unroll 2
    for (int k4 = 0; k4 < 64; ++k4) {
        int k = k4 * 4;
        float w0 = fc_w[(size_t)k * NN + n];
        float w1 = fc_w[(size_t)(k + 1) * NN + n];
        float w2 = fc_w[(size_t)(k + 2) * NN + n];
        float w3 = fc_w[(size_t)(k + 3) * NN + n];
#pragma unroll
        for (int i = 0; i < 16; ++i) {
            float4 cv = *(const float4*)&cl[bq * 16 + i][k];
            acc[i] += cv.x * w0 + cv.y * w1 + cv.z * w2 + cv.w * w3;
        }
    }
    float fb = fc_b[n];
#pragma unroll
    for (int i = 0; i < 16; ++i)
        out[(size_t)(bq * 16 + i) * NN + n] = acc[i] + fb;
}

// ---------------- host launcher ----------------
extern "C" void kernel_launch(void* const* d_in, const int* in_sizes, int n_in,
                              void* d_out, int out_size, void* d_ws, size_t ws_size,
                              hipStream_t stream) {
    const float* x_coords   = (const float*)d_in[0];
    const float* temporal   = (const float*)d_in[1];
    const int*   edge_index = (const int*)d_in[2];
    const float* edge_w     = (const float*)d_in[3];
    const int*   seq        = (const int*)d_in[4];
    const int*   lengths    = (const int*)d_in[5];
    const float* node_emb   = (const float*)d_in[6];
    const float* gcn1_w     = (const float*)d_in[7];
    const float* gcn1_b     = (const float*)d_in[8];
    const float* gcn2_w     = (const float*)d_in[9];
    const float* gcn2_b     = (const float*)d_in[10];
    const float* w_ih_f     = (const float*)d_in[11];
    const float* w_hh_f     = (const float*)d_in[12];
    const float* b_ih_f     = (const float*)d_in[13];
    const float* b_hh_f     = (const float*)d_in[14];
    const float* w_ih_b     = (const float*)d_in[15];
    const float* w_hh_b     = (const float*)d_in[16];
    const float* b_ih_b     = (const float*)d_in[17];
    const float* b_hh_b     = (const float*)d_in[18];
    const float* attn_w     = (const float*)d_in[19];
    const float* attn_b     = (const float*)d_in[20];
    const float* fc_w       = (const float*)d_in[21];
    const float* fc_b       = (const float*)d_in[22];
    float* out = (float*)d_out;

    char* base = (char*)d_ws;
    size_t off = 0;
    auto alloc = [&](size_t nbytes) -> void* {
        void* p = base + off;
        off = (off + nbytes + 255) & ~(size_t)255;
        return p;
    };
    int*   cnt     = (int*)alloc((size_t)2 * NN * 4);  // cnt + degw contiguous (one memset)
    float* degw    = (float*)(cnt + NN);
    float* dinv    = (float*)alloc((size_t)NN * 4);
    int*   rs      = (int*)alloc(((size_t)NN + 1) * 4);
    int*   cursor  = (int*)alloc((size_t)NN * 4);
    int*   partials= (int*)alloc(64 * 4);
    int*   ssrc    = (int*)alloc((size_t)NE * 4);
    float* sw      = (float*)alloc((size_t)NE * 4);
    float* h1      = (float*)alloc((size_t)NN * GH * 4);
    float* z1      = (float*)alloc((size_t)NN * GH * 4);
    float* a2      = h1;  // h1 dead after agg1
    float* z2      = (float*)alloc((size_t)NN * EMB * 4);
    float* se      = (float*)alloc((size_t)BB * TT * EMB * 4);
    float* xpf     = (float*)alloc((size_t)TT * BB * G4 * 4);
    float* xpb     = (float*)alloc((size_t)TT * BB * G4 * 4);
    float* hfo     = (float*)alloc((size_t)BB * TT * HH * 4);
    float* hbo     = (float*)alloc((size_t)BB * TT * HH * 4);
    float* ctx     = (float*)alloc((size_t)BB * 256 * 4);
    (void)ws_size; (void)in_sizes; (void)n_in; (void)out_size;

    hipMemsetAsync(cnt, 0, (size_t)2 * NN * 4, stream);

    hist_kernel<<<(NE + 255) / 256, 256, 0, stream>>>(edge_index, edge_w, cnt, degw);
    dinv_kernel<<<(NN + 255) / 256, 256, 0, stream>>>(degw, dinv);
    const int nblk = (NN + 1023) / 1024;  // 49
    scan1_kernel<<<nblk, 1024, 0, stream>>>(cnt, rs, partials);
    scan2_kernel<<<1, 64, 0, stream>>>(partials, nblk);
    scan3_kernel<<<nblk, 1024, 0, stream>>>(partials, rs, cursor);
    fill_kernel<<<(NE + 255) / 256, 256, 0, stream>>>(edge_index, edge_w, dinv, cursor, ssrc, sw);

    gemm1_kernel<<<(NN + 255) / 256, 256, 0, stream>>>(x_coords, temporal, node_emb, gcn1_w, h1);
    agg_kernel<<<(NN + 3) / 4, 256, 0, stream>>>(h1, rs, ssrc, sw, dinv, gcn1_b, 1, z1);
    agg_kernel<<<(NN + 3) / 4, 256, 0, stream>>>(z1, rs, ssrc, sw, dinv, (const float*)nullptr, 0, a2);
    gemm2_kernel<<<dim3((NN + 255) / 256, 2), 256, 0, stream>>>(a2, gcn2_w, gcn2_b, z2);

    gather_kernel<<<(BB * TT * 32 + 255) / 256, 256, 0, stream>>>(seq, z2, se);
    pregemm_kernel<<<dim3(TT * BB / 256, 8, 2), 256, 0, stream>>>(
        se, w_ih_f, w_ih_b, b_ih_f, b_hh_f, b_ih_b, b_hh_b, lengths, xpf, xpb);
    lstm_kernel<<<BB * 2, 512, 0, stream>>>(xpf, xpb, w_hh_f, w_hh_b, lengths, hfo, hbo);
    attn_kernel<<<BB, 256, 0, stream>>>(hfo, hbo, attn_w, attn_b, lengths, ctx);
    fc_kernel<<<(NN + 63) / 64, 256, 0, stream>>>(ctx, fc_w, fc_b, out);
}

// Round 2
// 700.402 us; speedup vs baseline: 1.0022x; 1.0022x over previous
//
#include <hip/hip_runtime.h>
#include <math.h>

#define NN 50000
#define NE 800000
#define EMB 128
#define GH 64
#define BB 64
#define TT 200
#define HH 128
#define G4 512
#define IND 134

__device__ __forceinline__ float sigf(float x) { return 1.0f / (1.0f + __expf(-x)); }
__device__ __forceinline__ float tanhf_(float x) { return 1.0f - 2.0f / (__expf(2.0f * x) + 1.0f); }
__device__ __forceinline__ void fma4(float4& a, float s, const float4 w) {
    a.x += s * w.x; a.y += s * w.y; a.z += s * w.z; a.w += s * w.w;
}

// ---------------- CSR build ----------------
__global__ void hist_kernel(const int* __restrict__ ei, const float* __restrict__ ew,
                            int* __restrict__ cnt, float* __restrict__ degw) {
    int e = blockIdx.x * 256 + threadIdx.x;
    if (e >= NE) return;
    int d = ei[NE + e];
    atomicAdd(&cnt[d], 1);
    atomicAdd(&degw[d], ew[e]);
}

__global__ void dinv_kernel(const float* __restrict__ degw, float* __restrict__ dinv) {
    int n = blockIdx.x * 256 + threadIdx.x;
    if (n >= NN) return;
    dinv[n] = rsqrtf(degw[n] + 1.0f);   // +1 self loop
}

__global__ __launch_bounds__(1024) void scan1_kernel(const int* __restrict__ cnt,
                                                     int* __restrict__ rs, int* __restrict__ partials) {
    __shared__ int s[1024];
    int gid = blockIdx.x * 1024 + threadIdx.x;
    int v = (gid < NN) ? cnt[gid] : 0;
    s[threadIdx.x] = v;
    __syncthreads();
    for (int off = 1; off < 1024; off <<= 1) {
        int add = (threadIdx.x >= (unsigned)off) ? s[threadIdx.x - off] : 0;
        __syncthreads();
        s[threadIdx.x] += add;
        __syncthreads();
    }
    if (gid < NN) rs[gid] = s[threadIdx.x] - v;  // exclusive
    if (threadIdx.x == 1023) partials[blockIdx.x] = s[1023];
}

__global__ void scan2_kernel(int* __restrict__ partials, int nblk) {
    if (threadIdx.x == 0) {
        int acc = 0;
        for (int i = 0; i < nblk; ++i) { int v = partials[i]; partials[i] = acc; acc += v; }
    }
}

__global__ __launch_bounds__(1024) void scan3_kernel(const int* __restrict__ partials,
                                                     int* __restrict__ rs, int* __restrict__ cursor) {
    int gid = blockIdx.x * 1024 + threadIdx.x;
    if (gid < NN) {
        int v = rs[gid] + partials[gid >> 10];
        rs[gid] = v;
        cursor[gid] = v;
    }
    if (gid == 0) rs[NN] = NE;
}

__global__ void fill_kernel(const int* __restrict__ ei, const float* __restrict__ ew,
                            const float* __restrict__ dinv, int* __restrict__ cursor,
                            int* __restrict__ ssrc, float* __restrict__ sw) {
    int e = blockIdx.x * 256 + threadIdx.x;
    if (e >= NE) return;
    int s = ei[e], d = ei[NE + e];
    int pos = atomicAdd(&cursor[d], 1);
    ssrc[pos] = s;
    sw[pos] = ew[e] * dinv[s] * dinv[d];
}

// ---------------- GCN layer 1 GEMM (fused concat, 134 -> 64) ----------------
__global__ __launch_bounds__(256) void gemm1_kernel(const float* __restrict__ coords,
                                                    const float* __restrict__ temporal,
                                                    const float* __restrict__ emb,
                                                    const float* __restrict__ W1,
                                                    float* __restrict__ h1) {
    __shared__ __align__(16) float wl[IND][GH];
    for (int i = threadIdx.x; i < IND * GH / 4; i += 256)
        ((float4*)wl)[i] = ((const float4*)W1)[i];
    __syncthreads();
    int n = blockIdx.x * 256 + threadIdx.x;
    if (n >= NN) return;
    float4 acc[16];
    float c0 = coords[2 * n], c1 = coords[2 * n + 1];
#pragma unroll
    for (int j = 0; j < 16; ++j) {
        float4 wa = *(const float4*)&wl[0][j * 4];
        float4 wb = *(const float4*)&wl[1][j * 4];
        float4 a;
        a.x = c0 * wa.x + c1 * wb.x; a.y = c0 * wa.y + c1 * wb.y;
        a.z = c0 * wa.z + c1 * wb.z; a.w = c0 * wa.w + c1 * wb.w;
        acc[j] = a;
    }
    const float4* er = (const float4*)(emb + (size_t)n * EMB);
#pragma unroll 2
    for (int k4 = 0; k4 < 32; ++k4) {
        float4 v = er[k4];
        int k = 2 + k4 * 4;
#pragma unroll
        for (int j = 0; j < 16; ++j) {
            fma4(acc[j], v.x, *(const float4*)&wl[k][j * 4]);
            fma4(acc[j], v.y, *(const float4*)&wl[k + 1][j * 4]);
            fma4(acc[j], v.z, *(const float4*)&wl[k + 2][j * 4]);
            fma4(acc[j], v.w, *(const float4*)&wl[k + 3][j * 4]);
        }
    }
    float t0 = temporal[4 * n], t1 = temporal[4 * n + 1], t2 = temporal[4 * n + 2], t3 = temporal[4 * n + 3];
#pragma unroll
    for (int j = 0; j < 16; ++j) {
        fma4(acc[j], t0, *(const float4*)&wl[130][j * 4]);
        fma4(acc[j], t1, *(const float4*)&wl[131][j * 4]);
        fma4(acc[j], t2, *(const float4*)&wl[132][j * 4]);
        fma4(acc[j], t3, *(const float4*)&wl[133][j * 4]);
        *(float4*)&h1[(size_t)n * GH + j * 4] = acc[j];
    }
}

// ---------------- symmetric-norm aggregation (64 features, CSR) ----------------
__global__ __launch_bounds__(256) void agg_kernel(const float* __restrict__ hin,
                                                  const int* __restrict__ rs,
                                                  const int* __restrict__ ssrc,
                                                  const float* __restrict__ sw,
                                                  const float* __restrict__ dinv,
                                                  const float* __restrict__ bias, int relu,
                                                  float* __restrict__ hout) {
    int lane = threadIdx.x & 63;
    int wid = threadIdx.x >> 6;
    int n = blockIdx.x * 4 + wid;
    if (n >= NN) return;
    float dv = dinv[n];
    float acc = hin[(size_t)n * GH + lane] * (dv * dv);  // self loop
    int i = rs[n], e1 = rs[n + 1];
    for (; i + 3 < e1; i += 4) {
        int s0 = ssrc[i], s1 = ssrc[i + 1], s2 = ssrc[i + 2], s3 = ssrc[i + 3];
        float w0 = sw[i], w1 = sw[i + 1], w2 = sw[i + 2], w3 = sw[i + 3];
        float a0 = hin[(size_t)s0 * GH + lane];
        float a1 = hin[(size_t)s1 * GH + lane];
        float a2 = hin[(size_t)s2 * GH + lane];
        float a3 = hin[(size_t)s3 * GH + lane];
        acc += a0 * w0 + a1 * w1 + a2 * w2 + a3 * w3;
    }
    for (; i < e1; ++i) acc += hin[(size_t)ssrc[i] * GH + lane] * sw[i];
    if (bias) acc += bias[lane];
    if (relu) acc = fmaxf(acc, 0.0f);
    hout[(size_t)n * GH + lane] = acc;
}

// ---------------- GCN layer 2 GEMM (64 -> 128) + bias ----------------
__global__ __launch_bounds__(256) void gemm2_kernel(const float* __restrict__ a2,
                                                    const float* __restrict__ W2,
                                                    const float* __restrict__ b2,
                                                    float* __restrict__ z2) {
    __shared__ __align__(16) float wl[GH][64];
    int j0 = blockIdx.y * 64;
    for (int i = threadIdx.x; i < GH * 16; i += 256) {
        int k = i >> 4, j4 = i & 15;
        *(float4*)&wl[k][j4 * 4] = *(const float4*)&W2[(size_t)k * EMB + j0 + j4 * 4];
    }
    __syncthreads();
    int n = blockIdx.x * 256 + threadIdx.x;
    if (n >= NN) return;
    float4 acc[16];
#pragma unroll
    for (int j = 0; j < 16; ++j) acc[j] = *(const float4*)&b2[j0 + j * 4];
    const float4* ar = (const float4*)(a2 + (size_t)n * GH);
#pragma unroll 2
    for (int k4 = 0; k4 < 16; ++k4) {
        float4 v = ar[k4];
        int k = k4 * 4;
#pragma unroll
        for (int j = 0; j < 16; ++j) {
            fma4(acc[j], v.x, *(const float4*)&wl[k][j * 4]);
            fma4(acc[j], v.y, *(const float4*)&wl[k + 1][j * 4]);
            fma4(acc[j], v.z, *(const float4*)&wl[k + 2][j * 4]);
            fma4(acc[j], v.w, *(const float4*)&wl[k + 3][j * 4]);
        }
    }
#pragma unroll
    for (int j = 0; j < 16; ++j)
        *(float4*)&z2[(size_t)n * EMB + j0 + j * 4] = acc[j];
}

// ---------------- gather sequence embeddings ----------------
__global__ void gather_kernel(const int* __restrict__ seq, const float* __restrict__ z2,
                              float* __restrict__ se) {
    int idx = blockIdx.x * 256 + threadIdx.x;
    if (idx >= BB * TT * 32) return;
    int r = idx >> 5, q = idx & 31;
    int node = seq[r];
    ((float4*)se)[(size_t)r * 32 + q] = ((const float4*)z2)[(size_t)node * 32 + q];
}

// ---------------- pre-GEMM: x @ w_ih.T + biases, layout [T][B][512] ----------------
__global__ __launch_bounds__(256) void pregemm_kernel(const float* __restrict__ se,
                                                      const float* __restrict__ w_ih_f,
                                                      const float* __restrict__ w_ih_b,
                                                      const float* __restrict__ b_ih_f,
                                                      const float* __restrict__ b_hh_f,
                                                      const float* __restrict__ b_ih_b,
                                                      const float* __restrict__ b_hh_b,
                                                      const int* __restrict__ lengths,
                                                      float* __restrict__ xpf,
                                                      float* __restrict__ xpb) {
    int dir = blockIdx.z;
    const float* w_ih = dir ? w_ih_b : w_ih_f;
    int u0 = blockIdx.y * 64;
    __shared__ __align__(16) float wl[64][EMB];
    __shared__ float bs[64];
    {
        const float4* src = (const float4*)(w_ih + (size_t)u0 * EMB);
        for (int i = threadIdx.x; i < 64 * EMB / 4; i += 256) ((float4*)wl)[i] = src[i];
        if (threadIdx.x < 64) {
            int u = u0 + threadIdx.x;
            bs[threadIdx.x] = dir ? (b_ih_b[u] + b_hh_b[u]) : (b_ih_f[u] + b_hh_f[u]);
        }
    }
    __syncthreads();
    int m = blockIdx.x * 256 + threadIdx.x;  // m = t*64 + b
    if (m >= TT * BB) return;
    int t = m >> 6, b = m & 63;
    int tsrc = t;
    if (dir) {
        int len = lengths[b];
        if (t >= len) return;
        tsrc = len - 1 - t;
    }
    const float4* row = (const float4*)(se + ((size_t)b * TT + tsrc) * EMB);
    float accs[64];
#pragma unroll
    for (int j = 0; j < 64; ++j) accs[j] = bs[j];
#pragma unroll 2
    for (int k4 = 0; k4 < 32; ++k4) {
        float4 xv = row[k4];
#pragma unroll
        for (int j = 0; j < 64; ++j) {
            float4 wv = *(const float4*)&wl[j][k4 * 4];
            accs[j] += xv.x * wv.x + xv.y * wv.y + xv.z * wv.z + xv.w * wv.w;
        }
    }
    float* xp = dir ? xpb : xpf;
#pragma unroll
    for (int j4 = 0; j4 < 16; ++j4) {
        float4 o = make_float4(accs[j4 * 4], accs[j4 * 4 + 1], accs[j4 * 4 + 2], accs[j4 * 4 + 3]);
        *(float4*)&xp[(size_t)m * G4 + u0 + j4 * 4] = o;
    }
}

// ---------------- LSTM recurrence ----------------
// 512 threads, tid = unit*4 + gate. Weight row (128 floats) held in 32 NAMED
// float4 registers (macro-expanded -> cannot be demoted to scratch; round-1
// version had VGPR_Count=88 => w[] lived in scratch, 256KB/step L2 re-reads
// dominated at 0.95us/step). Gate exchange via 3x shfl_xor in each 4-lane
// quad; h double-buffered in LDS => ONE barrier/step; xp prefetched 1 step.
#define LSTM_LW(i) float4 W##i = wr[i];
#define LSTM_FMA(i) { float4 hv = h4[i]; \
    a0 += W##i.x * hv.x; a1 += W##i.y * hv.y; a2 += W##i.z * hv.z; a3 += W##i.w * hv.w; }

__global__ __launch_bounds__(512, 1) void lstm_kernel(const float* __restrict__ xpf,
                                                      const float* __restrict__ xpb,
                                                      const float* __restrict__ w_hh_f,
                                                      const float* __restrict__ w_hh_b,
                                                      const int* __restrict__ lengths,
                                                      float* __restrict__ hfo,
                                                      float* __restrict__ hbo) {
    int chain = blockIdx.x;
    int dir = chain & 1, b = chain >> 1;
    const float* w_hh = dir ? w_hh_b : w_hh_f;
    const float* xp = dir ? xpb : xpf;
    float* ho = dir ? hbo : hfo;
    int tid = threadIdx.x;
    int u = tid >> 2, g = tid & 3;   // unit 0..127, gate 0..3 (i,f,g,o)
    int len = lengths[b];

    const float4* wr = (const float4*)(w_hh + (size_t)(g * HH + u) * HH);
    LSTM_LW(0) LSTM_LW(1) LSTM_LW(2) LSTM_LW(3) LSTM_LW(4) LSTM_LW(5) LSTM_LW(6) LSTM_LW(7)
    LSTM_LW(8) LSTM_LW(9) LSTM_LW(10) LSTM_LW(11) LSTM_LW(12) LSTM_LW(13) LSTM_LW(14) LSTM_LW(15)
    LSTM_LW(16) LSTM_LW(17) LSTM_LW(18) LSTM_LW(19) LSTM_LW(20) LSTM_LW(21) LSTM_LW(22) LSTM_LW(23)
    LSTM_LW(24) LSTM_LW(25) LSTM_LW(26) LSTM_LW(27) LSTM_LW(28) LSTM_LW(29) LSTM_LW(30) LSTM_LW(31)

    __shared__ __align__(16) float hl[2][HH];
    if (tid < HH) hl[0][tid] = 0.0f;
    __syncthreads();

    const float* xpt = xp + (size_t)b * G4 + g * HH + u;
    float cst = 0.0f;
    float xcur = xpt[0];
    for (int t = 0; t < len; ++t) {
        float xnext = (t + 1 < len) ? xpt[(size_t)(t + 1) * BB * G4] : 0.0f;
        const float4* h4 = (const float4*)hl[t & 1];
        float a0 = 0.0f, a1 = 0.0f, a2 = 0.0f, a3 = 0.0f;
        LSTM_FMA(0) LSTM_FMA(1) LSTM_FMA(2) LSTM_FMA(3) LSTM_FMA(4) LSTM_FMA(5) LSTM_FMA(6) LSTM_FMA(7)
        LSTM_FMA(8) LSTM_FMA(9) LSTM_FMA(10) LSTM_FMA(11) LSTM_FMA(12) LSTM_FMA(13) LSTM_FMA(14) LSTM_FMA(15)
        LSTM_FMA(16) LSTM_FMA(17) LSTM_FMA(18) LSTM_FMA(19) LSTM_FMA(20) LSTM_FMA(21) LSTM_FMA(22) LSTM_FMA(23)
        LSTM_FMA(24) LSTM_FMA(25) LSTM_FMA(26) LSTM_FMA(27) LSTM_FMA(28) LSTM_FMA(29) LSTM_FMA(30) LSTM_FMA(31)
        float acc = ((a0 + a1) + (a2 + a3)) + xcur;   // full pre-activation for gate g
        // butterfly: collect all four gate sums into every lane of the quad
        float sb = __shfl_xor(acc, 1, 64);   // S_{g^1}
        float sc = __shfl_xor(acc, 2, 64);   // S_{g^2}
        float sd = __shfl_xor(sb, 2, 64);    // S_{g^3}
        // S_j sits in var index m = g ^ j  (vars: [acc, sb, sc, sd])
        float si = (g == 0) ? acc : (g == 1) ? sb : (g == 2) ? sc : sd;
        float sf = (g == 0) ? sb : (g == 1) ? acc : (g == 2) ? sd : sc;
        float sg = (g == 0) ? sc : (g == 1) ? sd : (g == 2) ? acc : sb;
        float so = (g == 0) ? sd : (g == 1) ? sc : (g == 2) ? sb : acc;
        cst = sigf(sf) * cst + sigf(si) * tanhf_(sg);
        float h = sigf(so) * tanhf_(cst);
        if (g == 0) {
            hl[(t + 1) & 1][u] = h;
            int tt = dir ? (len - 1 - t) : t;
            ho[((size_t)b * TT + tt) * HH + u] = h;
        }
        __syncthreads();
        xcur = xnext;
    }
}

// ---------------- masked attention pooling ----------------
__global__ __launch_bounds__(256) void attn_kernel(const float* __restrict__ hf,
                                                   const float* __restrict__ hb,
                                                   const float* __restrict__ attn_w,
                                                   const float* __restrict__ attn_b,
                                                   const int* __restrict__ lengths,
                                                   float* __restrict__ ctx) {
    int b = blockIdx.x;
    int tid = threadIdx.x;
    int len = lengths[b];
    __shared__ __align__(16) float wl[256];
    __shared__ float pl[256];
    __shared__ float red[256];
    wl[tid] = attn_w[tid];
    __syncthreads();
    float sc = -3.0e38f;
    if (tid < len) {
        const float4* rf = (const float4*)(hf + ((size_t)b * TT + tid) * HH);
        const float4* rb = (const float4*)(hb + ((size_t)b * TT + tid) * HH);
        const float4* w4 = (const float4*)wl;
        float s = attn_b[0];
        for (int k4 = 0; k4 < 32; ++k4) {
            float4 a = rf[k4], ww = w4[k4];
            s += a.x * ww.x + a.y * ww.y + a.z * ww.z + a.w * ww.w;
        }
        for (int k4 = 0; k4 < 32; ++k4) {
            float4 a = rb[k4], ww = w4[32 + k4];
            s += a.x * ww.x + a.y * ww.y + a.z * ww.z + a.w * ww.w;
        }
        sc = s;
    }
    red[tid] = sc;
    __syncthreads();
    for (int off = 128; off > 0; off >>= 1) {
        if (tid < off) red[tid] = fmaxf(red[tid], red[tid + off]);
        __syncthreads();
    }
    float mx = red[0];
    __syncthreads();
    float e = (tid < len) ? __expf(sc - mx) : 0.0f;
    red[tid] = e;
    __syncthreads();
    for (int off = 128; off > 0; off >>= 1) {
        if (tid < off) red[tid] += red[tid + off];
        __syncthreads();
    }
    float inv = 1.0f / red[0];
    pl[tid] = e * inv;
    __syncthreads();
    float acc = 0.0f;
    const float* basep = (tid < HH) ? (hf + (size_t)b * TT * HH + tid)
                                    : (hb + (size_t)b * TT * HH + (tid - HH));
#pragma unroll 4
    for (int t = 0; t < len; ++t) acc += pl[t] * basep[(size_t)t * HH];
    ctx[(size_t)b * 256 + tid] = acc;
}

// ---------------- final FC: [64,256] @ [256,N] + b ----------------
__global__ __launch_bounds__(256) void fc_kernel(const float* __restrict__ ctx,
                                                 const float* __restrict__ fc_w,
                                                 const float* __restrict__ fc_b,
                                                 float* __restrict__ out) {
    __shared__ __align__(16) float cl[64][256];
    for (int i = threadIdx.x; i < 64 * 256 / 4; i += 256)
        ((float4*)cl)[i] = ((const float4*)ctx)[i];
    __syncthreads();
    int nb = threadIdx.x & 63;
    int bq = threadIdx.x >> 6;
    int n = blockIdx.x * 64 + nb;
    if (n >= NN) return;
    float acc[16];
#pragma unroll
    for (int i = 0; i < 16; ++i) acc[i] = 0.0f;
#pragma unroll 2
    for (int k4 = 0; k4 < 64; ++k4) {
        int k = k4 * 4;
        float w0 = fc_w[(size_t)k * NN + n];
        float w1 = fc_w[(size_t)(k + 1) * NN + n];
        float w2 = fc_w[(size_t)(k + 2) * NN + n];
        float w3 = fc_w[(size_t)(k + 3) * NN + n];
#pragma unroll
        for (int i = 0; i < 16; ++i) {
            float4 cv = *(const float4*)&cl[bq * 16 + i][k];
            acc[i] += cv.x * w0 + cv.y * w1 + cv.z * w2 + cv.w * w3;
        }
    }
    float fb = fc_b[n];
#pragma unroll
    for (int i = 0; i < 16; ++i)
        out[(size_t)(bq * 16 + i) * NN + n] = acc[i] + fb;
}

// ---------------- host launcher ----------------
extern "C" void kernel_launch(void* const* d_in, const int* in_sizes, int n_in,
                              void* d_out, int out_size, void* d_ws, size_t ws_size,
                              hipStream_t stream) {
    const float* x_coords   = (const float*)d_in[0];
    const float* temporal   = (const float*)d_in[1];
    const int*   edge_index = (const int*)d_in[2];
    const float* edge_w     = (const float*)d_in[3];
    const int*   seq        = (const int*)d_in[4];
    const int*   lengths    = (const int*)d_in[5];
    const float* node_emb   = (const float*)d_in[6];
    const float* gcn1_w     = (const float*)d_in[7];
    const float* gcn1_b     = (const float*)d_in[8];
    const float* gcn2_w     = (const float*)d_in[9];
    const float* gcn2_b     = (const float*)d_in[10];
    const float* w_ih_f     = (const float*)d_in[11];
    const float* w_hh_f     = (const float*)d_in[12];
    const float* b_ih_f     = (const float*)d_in[13];
    const float* b_hh_f     = (const float*)d_in[14];
    const float* w_ih_b     = (const float*)d_in[15];
    const float* w_hh_b     = (const float*)d_in[16];
    const float* b_ih_b     = (const float*)d_in[17];
    const float* b_hh_b     = (const float*)d_in[18];
    const float* attn_w     = (const float*)d_in[19];
    const float* attn_b     = (const float*)d_in[20];
    const float* fc_w       = (const float*)d_in[21];
    const float* fc_b       = (const float*)d_in[22];
    float* out = (float*)d_out;

    char* base = (char*)d_ws;
    size_t off = 0;
    auto alloc = [&](size_t nbytes) -> void* {
        void* p = base + off;
        off = (off + nbytes + 255) & ~(size_t)255;
        return p;
    };
    int*   cnt     = (int*)alloc((size_t)2 * NN * 4);  // cnt + degw contiguous (one memset)
    float* degw    = (float*)(cnt + NN);
    float* dinv    = (float*)alloc((size_t)NN * 4);
    int*   rs      = (int*)alloc(((size_t)NN + 1) * 4);
    int*   cursor  = (int*)alloc((size_t)NN * 4);
    int*   partials= (int*)alloc(64 * 4);
    int*   ssrc    = (int*)alloc((size_t)NE * 4);
    float* sw      = (float*)alloc((size_t)NE * 4);
    float* h1      = (float*)alloc((size_t)NN * GH * 4);
    float* z1      = (float*)alloc((size_t)NN * GH * 4);
    float* a2      = h1;  // h1 dead after agg1
    float* z2      = (float*)alloc((size_t)NN * EMB * 4);
    float* se      = (float*)alloc((size_t)BB * TT * EMB * 4);
    float* xpf     = (float*)alloc((size_t)TT * BB * G4 * 4);
    float* xpb     = (float*)alloc((size_t)TT * BB * G4 * 4);
    float* hfo     = (float*)alloc((size_t)BB * TT * HH * 4);
    float* hbo     = (float*)alloc((size_t)BB * TT * HH * 4);
    float* ctx     = (float*)alloc((size_t)BB * 256 * 4);
    (void)ws_size; (void)in_sizes; (void)n_in; (void)out_size;

    hipMemsetAsync(cnt, 0, (size_t)2 * NN * 4, stream);

    hist_kernel<<<(NE + 255) / 256, 256, 0, stream>>>(edge_index, edge_w, cnt, degw);
    dinv_kernel<<<(NN + 255) / 256, 256, 0, stream>>>(degw, dinv);
    const int nblk = (NN + 1023) / 1024;  // 49
    scan1_kernel<<<nblk, 1024, 0, stream>>>(cnt, rs, partials);
    scan2_kernel<<<1, 64, 0, stream>>>(partials, nblk);
    scan3_kernel<<<nblk, 1024, 0, stream>>>(partials, rs, cursor);
    fill_kernel<<<(NE + 255) / 256, 256, 0, stream>>>(edge_index, edge_w, dinv, cursor, ssrc, sw);

    gemm1_kernel<<<(NN + 255) / 256, 256, 0, stream>>>(x_coords, temporal, node_emb, gcn1_w, h1);
    agg_kernel<<<(NN + 3) / 4, 256, 0, stream>>>(h1, rs, ssrc, sw, dinv, gcn1_b, 1, z1);
    agg_kernel<<<(NN + 3) / 4, 256, 0, stream>>>(z1, rs, ssrc, sw, dinv, (const float*)nullptr, 0, a2);
    gemm2_kernel<<<dim3((NN + 255) / 256, 2), 256, 0, stream>>>(a2, gcn2_w, gcn2_b, z2);

    gather_kernel<<<(BB * TT * 32 + 255) / 256, 256, 0, stream>>>(seq, z2, se);
    pregemm_kernel<<<dim3(TT * BB / 256, 8, 2), 256, 0, stream>>>(
        se, w_ih_f, w_ih_b, b_ih_f, b_hh_f, b_ih_b, b_hh_b, lengths, xpf, xpb);
    lstm_kernel<<<BB * 2, 512, 0, stream>>>(xpf, xpb, w_hh_f, w_hh_b, lengths, hfo, hbo);
    attn_kernel<<<BB, 256, 0, stream>>>(hfo, hbo, attn_w, attn_b, lengths, ctx);
    fc_kernel<<<(NN + 63) / 64, 256, 0, stream>>>(ctx, fc_w, fc_b, out);
}

// Round 3
// 692.686 us; speedup vs baseline: 1.0134x; 1.0111x over previous
//
#include <hip/hip_runtime.h>
#include <math.h>

#define NN 50000
#define NE 800000
#define EMB 128
#define GH 64
#define BB 64
#define TT 200
#define HH 128
#define G4 512
#define IND 134

__device__ __forceinline__ float sigf(float x) { return 1.0f / (1.0f + __expf(-x)); }
__device__ __forceinline__ float tanhf_(float x) { return 1.0f - 2.0f / (__expf(2.0f * x) + 1.0f); }
__device__ __forceinline__ void fma4(float4& a, float s, const float4 w) {
    a.x += s * w.x; a.y += s * w.y; a.z += s * w.z; a.w += s * w.w;
}

// ---------------- CSR build ----------------
__global__ void hist_kernel(const int* __restrict__ ei, const float* __restrict__ ew,
                            int* __restrict__ cnt, float* __restrict__ degw) {
    int e = blockIdx.x * 256 + threadIdx.x;
    if (e >= NE) return;
    int d = ei[NE + e];
    atomicAdd(&cnt[d], 1);
    atomicAdd(&degw[d], ew[e]);
}

__global__ void dinv_kernel(const float* __restrict__ degw, float* __restrict__ dinv) {
    int n = blockIdx.x * 256 + threadIdx.x;
    if (n >= NN) return;
    dinv[n] = rsqrtf(degw[n] + 1.0f);   // +1 self loop
}

__global__ __launch_bounds__(1024) void scan1_kernel(const int* __restrict__ cnt,
                                                     int* __restrict__ rs, int* __restrict__ partials) {
    __shared__ int s[1024];
    int gid = blockIdx.x * 1024 + threadIdx.x;
    int v = (gid < NN) ? cnt[gid] : 0;
    s[threadIdx.x] = v;
    __syncthreads();
    for (int off = 1; off < 1024; off <<= 1) {
        int add = (threadIdx.x >= (unsigned)off) ? s[threadIdx.x - off] : 0;
        __syncthreads();
        s[threadIdx.x] += add;
        __syncthreads();
    }
    if (gid < NN) rs[gid] = s[threadIdx.x] - v;  // exclusive
    if (threadIdx.x == 1023) partials[blockIdx.x] = s[1023];
}

__global__ void scan2_kernel(int* __restrict__ partials, int nblk) {
    if (threadIdx.x == 0) {
        int acc = 0;
        for (int i = 0; i < nblk; ++i) { int v = partials[i]; partials[i] = acc; acc += v; }
    }
}

__global__ __launch_bounds__(1024) void scan3_kernel(const int* __restrict__ partials,
                                                     int* __restrict__ rs, int* __restrict__ cursor) {
    int gid = blockIdx.x * 1024 + threadIdx.x;
    if (gid < NN) {
        int v = rs[gid] + partials[gid >> 10];
        rs[gid] = v;
        cursor[gid] = v;
    }
    if (gid == 0) rs[NN] = NE;
}

__global__ void fill_kernel(const int* __restrict__ ei, const float* __restrict__ ew,
                            const float* __restrict__ dinv, int* __restrict__ cursor,
                            int* __restrict__ ssrc, float* __restrict__ sw) {
    int e = blockIdx.x * 256 + threadIdx.x;
    if (e >= NE) return;
    int s = ei[e], d = ei[NE + e];
    int pos = atomicAdd(&cursor[d], 1);
    ssrc[pos] = s;
    sw[pos] = ew[e] * dinv[s] * dinv[d];
}

// ---------------- GCN layer 1 GEMM (fused concat, 134 -> 64) ----------------
__global__ __launch_bounds__(256) void gemm1_kernel(const float* __restrict__ coords,
                                                    const float* __restrict__ temporal,
                                                    const float* __restrict__ emb,
                                                    const float* __restrict__ W1,
                                                    float* __restrict__ h1) {
    __shared__ __align__(16) float wl[IND][GH];
    for (int i = threadIdx.x; i < IND * GH / 4; i += 256)
        ((float4*)wl)[i] = ((const float4*)W1)[i];
    __syncthreads();
    int n = blockIdx.x * 256 + threadIdx.x;
    if (n >= NN) return;
    float4 acc[16];
    float c0 = coords[2 * n], c1 = coords[2 * n + 1];
#pragma unroll
    for (int j = 0; j < 16; ++j) {
        float4 wa = *(const float4*)&wl[0][j * 4];
        float4 wb = *(const float4*)&wl[1][j * 4];
        float4 a;
        a.x = c0 * wa.x + c1 * wb.x; a.y = c0 * wa.y + c1 * wb.y;
        a.z = c0 * wa.z + c1 * wb.z; a.w = c0 * wa.w + c1 * wb.w;
        acc[j] = a;
    }
    const float4* er = (const float4*)(emb + (size_t)n * EMB);
#pragma unroll 2
    for (int k4 = 0; k4 < 32; ++k4) {
        float4 v = er[k4];
        int k = 2 + k4 * 4;
#pragma unroll
        for (int j = 0; j < 16; ++j) {
            fma4(acc[j], v.x, *(const float4*)&wl[k][j * 4]);
            fma4(acc[j], v.y, *(const float4*)&wl[k + 1][j * 4]);
            fma4(acc[j], v.z, *(const float4*)&wl[k + 2][j * 4]);
            fma4(acc[j], v.w, *(const float4*)&wl[k + 3][j * 4]);
        }
    }
    float t0 = temporal[4 * n], t1 = temporal[4 * n + 1], t2 = temporal[4 * n + 2], t3 = temporal[4 * n + 3];
#pragma unroll
    for (int j = 0; j < 16; ++j) {
        fma4(acc[j], t0, *(const float4*)&wl[130][j * 4]);
        fma4(acc[j], t1, *(const float4*)&wl[131][j * 4]);
        fma4(acc[j], t2, *(const float4*)&wl[132][j * 4]);
        fma4(acc[j], t3, *(const float4*)&wl[133][j * 4]);
        *(float4*)&h1[(size_t)n * GH + j * 4] = acc[j];
    }
}

// ---------------- symmetric-norm aggregation (64 features, CSR) ----------------
__global__ __launch_bounds__(256) void agg_kernel(const float* __restrict__ hin,
                                                  const int* __restrict__ rs,
                                                  const int* __restrict__ ssrc,
                                                  const float* __restrict__ sw,
                                                  const float* __restrict__ dinv,
                                                  const float* __restrict__ bias, int relu,
                                                  float* __restrict__ hout) {
    int lane = threadIdx.x & 63;
    int wid = threadIdx.x >> 6;
    int n = blockIdx.x * 4 + wid;
    if (n >= NN) return;
    float dv = dinv[n];
    float acc = hin[(size_t)n * GH + lane] * (dv * dv);  // self loop
    int i = rs[n], e1 = rs[n + 1];
    for (; i + 3 < e1; i += 4) {
        int s0 = ssrc[i], s1 = ssrc[i + 1], s2 = ssrc[i + 2], s3 = ssrc[i + 3];
        float w0 = sw[i], w1 = sw[i + 1], w2 = sw[i + 2], w3 = sw[i + 3];
        float a0 = hin[(size_t)s0 * GH + lane];
        float a1 = hin[(size_t)s1 * GH + lane];
        float a2 = hin[(size_t)s2 * GH + lane];
        float a3 = hin[(size_t)s3 * GH + lane];
        acc += a0 * w0 + a1 * w1 + a2 * w2 + a3 * w3;
    }
    for (; i < e1; ++i) acc += hin[(size_t)ssrc[i] * GH + lane] * sw[i];
    if (bias) acc += bias[lane];
    if (relu) acc = fmaxf(acc, 0.0f);
    hout[(size_t)n * GH + lane] = acc;
}

// ---------------- GCN layer 2 GEMM (64 -> 128) + bias ----------------
__global__ __launch_bounds__(256) void gemm2_kernel(const float* __restrict__ a2,
                                                    const float* __restrict__ W2,
                                                    const float* __restrict__ b2,
                                                    float* __restrict__ z2) {
    __shared__ __align__(16) float wl[GH][64];
    int j0 = blockIdx.y * 64;
    for (int i = threadIdx.x; i < GH * 16; i += 256) {
        int k = i >> 4, j4 = i & 15;
        *(float4*)&wl[k][j4 * 4] = *(const float4*)&W2[(size_t)k * EMB + j0 + j4 * 4];
    }
    __syncthreads();
    int n = blockIdx.x * 256 + threadIdx.x;
    if (n >= NN) return;
    float4 acc[16];
#pragma unroll
    for (int j = 0; j < 16; ++j) acc[j] = *(const float4*)&b2[j0 + j * 4];
    const float4* ar = (const float4*)(a2 + (size_t)n * GH);
#pragma unroll 2
    for (int k4 = 0; k4 < 16; ++k4) {
        float4 v = ar[k4];
        int k = k4 * 4;
#pragma unroll
        for (int j = 0; j < 16; ++j) {
            fma4(acc[j], v.x, *(const float4*)&wl[k][j * 4]);
            fma4(acc[j], v.y, *(const float4*)&wl[k + 1][j * 4]);
            fma4(acc[j], v.z, *(const float4*)&wl[k + 2][j * 4]);
            fma4(acc[j], v.w, *(const float4*)&wl[k + 3][j * 4]);
        }
    }
#pragma unroll
    for (int j = 0; j < 16; ++j)
        *(float4*)&z2[(size_t)n * EMB + j0 + j * 4] = acc[j];
}

// ---------------- gather sequence embeddings ----------------
__global__ void gather_kernel(const int* __restrict__ seq, const float* __restrict__ z2,
                              float* __restrict__ se) {
    int idx = blockIdx.x * 256 + threadIdx.x;
    if (idx >= BB * TT * 32) return;
    int r = idx >> 5, q = idx & 31;
    int node = seq[r];
    ((float4*)se)[(size_t)r * 32 + q] = ((const float4*)z2)[(size_t)node * 32 + q];
}

// ---------------- pre-GEMM: x @ w_ih.T + biases, layout [T][B][512] ----------------
__global__ __launch_bounds__(256) void pregemm_kernel(const float* __restrict__ se,
                                                      const float* __restrict__ w_ih_f,
                                                      const float* __restrict__ w_ih_b,
                                                      const float* __restrict__ b_ih_f,
                                                      const float* __restrict__ b_hh_f,
                                                      const float* __restrict__ b_ih_b,
                                                      const float* __restrict__ b_hh_b,
                                                      const int* __restrict__ lengths,
                                                      float* __restrict__ xpf,
                                                      float* __restrict__ xpb) {
    int dir = blockIdx.z;
    const float* w_ih = dir ? w_ih_b : w_ih_f;
    int u0 = blockIdx.y * 64;
    __shared__ __align__(16) float wl[64][EMB];
    __shared__ float bs[64];
    {
        const float4* src = (const float4*)(w_ih + (size_t)u0 * EMB);
        for (int i = threadIdx.x; i < 64 * EMB / 4; i += 256) ((float4*)wl)[i] = src[i];
        if (threadIdx.x < 64) {
            int u = u0 + threadIdx.x;
            bs[threadIdx.x] = dir ? (b_ih_b[u] + b_hh_b[u]) : (b_ih_f[u] + b_hh_f[u]);
        }
    }
    __syncthreads();
    int m = blockIdx.x * 256 + threadIdx.x;  // m = t*64 + b
    if (m >= TT * BB) return;
    int t = m >> 6, b = m & 63;
    int tsrc = t;
    if (dir) {
        int len = lengths[b];
        if (t >= len) return;
        tsrc = len - 1 - t;
    }
    const float4* row = (const float4*)(se + ((size_t)b * TT + tsrc) * EMB);
    float accs[64];
#pragma unroll
    for (int j = 0; j < 64; ++j) accs[j] = bs[j];
#pragma unroll 2
    for (int k4 = 0; k4 < 32; ++k4) {
        float4 xv = row[k4];
#pragma unroll
        for (int j = 0; j < 64; ++j) {
            float4 wv = *(const float4*)&wl[j][k4 * 4];
            accs[j] += xv.x * wv.x + xv.y * wv.y + xv.z * wv.z + xv.w * wv.w;
        }
    }
    float* xp = dir ? xpb : xpf;
#pragma unroll
    for (int j4 = 0; j4 < 16; ++j4) {
        float4 o = make_float4(accs[j4 * 4], accs[j4 * 4 + 1], accs[j4 * 4 + 2], accs[j4 * 4 + 3]);
        *(float4*)&xp[(size_t)m * G4 + u0 + j4 * 4] = o;
    }
}

// ---------------- LSTM recurrence ----------------
// 512 threads, tid = unit*4 + gate. Weight row (128 floats) in 32 float4
// that are PINNED via empty asm with "+v" constraints: round-2 showed the
// compiler rematerializes plain loads back into the loop (VGPR_Count=80 <
// 128 needed), keeping the kernel L1/L2-BW-bound on weight re-reads. The
// "+v" pin makes each value opaque so it MUST stay register-resident.
// Activation is applied to the lane's OWN gate before the butterfly so each
// transcendental is computed once per quad (10 -> ~4 trans ops per lane).
#define LSTM_LW(i) float4 W##i = wr[i]; \
    asm volatile("" : "+v"(W##i.x), "+v"(W##i.y), "+v"(W##i.z), "+v"(W##i.w));
#define LSTM_FMA(i) { float4 hv = h4[i]; \
    a0 += W##i.x * hv.x; a1 += W##i.y * hv.y; a2 += W##i.z * hv.z; a3 += W##i.w * hv.w; }

__global__ __launch_bounds__(512, 1) void lstm_kernel(const float* __restrict__ xpf,
                                                      const float* __restrict__ xpb,
                                                      const float* __restrict__ w_hh_f,
                                                      const float* __restrict__ w_hh_b,
                                                      const int* __restrict__ lengths,
                                                      float* __restrict__ hfo,
                                                      float* __restrict__ hbo) {
    int chain = blockIdx.x;
    int dir = chain & 1, b = chain >> 1;
    const float* w_hh = dir ? w_hh_b : w_hh_f;
    const float* xp = dir ? xpb : xpf;
    float* ho = dir ? hbo : hfo;
    int tid = threadIdx.x;
    int u = tid >> 2, g = tid & 3;   // unit 0..127, gate 0..3 (i,f,g,o)
    int len = lengths[b];

    const float4* wr = (const float4*)(w_hh + (size_t)(g * HH + u) * HH);
    LSTM_LW(0) LSTM_LW(1) LSTM_LW(2) LSTM_LW(3) LSTM_LW(4) LSTM_LW(5) LSTM_LW(6) LSTM_LW(7)
    LSTM_LW(8) LSTM_LW(9) LSTM_LW(10) LSTM_LW(11) LSTM_LW(12) LSTM_LW(13) LSTM_LW(14) LSTM_LW(15)
    LSTM_LW(16) LSTM_LW(17) LSTM_LW(18) LSTM_LW(19) LSTM_LW(20) LSTM_LW(21) LSTM_LW(22) LSTM_LW(23)
    LSTM_LW(24) LSTM_LW(25) LSTM_LW(26) LSTM_LW(27) LSTM_LW(28) LSTM_LW(29) LSTM_LW(30) LSTM_LW(31)

    __shared__ __align__(16) float hl[2][HH];
    if (tid < HH) hl[0][tid] = 0.0f;
    __syncthreads();

    const float* xpt = xp + (size_t)b * G4 + g * HH + u;
    float cst = 0.0f;
    float xcur = xpt[0];
    for (int t = 0; t < len; ++t) {
        float xnext = (t + 1 < len) ? xpt[(size_t)(t + 1) * BB * G4] : 0.0f;
        const float4* h4 = (const float4*)hl[t & 1];
        float a0 = 0.0f, a1 = 0.0f, a2 = 0.0f, a3 = 0.0f;
        LSTM_FMA(0) LSTM_FMA(1) LSTM_FMA(2) LSTM_FMA(3) LSTM_FMA(4) LSTM_FMA(5) LSTM_FMA(6) LSTM_FMA(7)
        LSTM_FMA(8) LSTM_FMA(9) LSTM_FMA(10) LSTM_FMA(11) LSTM_FMA(12) LSTM_FMA(13) LSTM_FMA(14) LSTM_FMA(15)
        LSTM_FMA(16) LSTM_FMA(17) LSTM_FMA(18) LSTM_FMA(19) LSTM_FMA(20) LSTM_FMA(21) LSTM_FMA(22) LSTM_FMA(23)
        LSTM_FMA(24) LSTM_FMA(25) LSTM_FMA(26) LSTM_FMA(27) LSTM_FMA(28) LSTM_FMA(29) LSTM_FMA(30) LSTM_FMA(31)
        float acc = ((a0 + a1) + (a2 + a3)) + xcur;   // own gate pre-activation
        // activate own gate BEFORE exchange (once per quad per gate)
        float a_own = (g == 2) ? tanhf_(acc) : sigf(acc);
        // butterfly: collect all four ACTIVATED gate values into the quad
        float sb = __shfl_xor(a_own, 1, 64);   // act_{g^1}
        float sc = __shfl_xor(a_own, 2, 64);   // act_{g^2}
        float sd = __shfl_xor(sb, 2, 64);      // act_{g^3}
        // act_j sits in var index m = g ^ j  (vars: [a_own, sb, sc, sd])
        float si = (g == 0) ? a_own : (g == 1) ? sb : (g == 2) ? sc : sd;
        float sf = (g == 0) ? sb : (g == 1) ? a_own : (g == 2) ? sd : sc;
        float sg = (g == 0) ? sc : (g == 1) ? sd : (g == 2) ? a_own : sb;
        float so = (g == 0) ? sd : (g == 1) ? sc : (g == 2) ? sb : a_own;
        cst = sf * cst + si * sg;
        float h = so * tanhf_(cst);
        if (g == 0) {
            hl[(t + 1) & 1][u] = h;
            int tt = dir ? (len - 1 - t) : t;
            ho[((size_t)b * TT + tt) * HH + u] = h;
        }
        __syncthreads();
        xcur = xnext;
    }
}

// ---------------- masked attention pooling ----------------
__global__ __launch_bounds__(256) void attn_kernel(const float* __restrict__ hf,
                                                   const float* __restrict__ hb,
                                                   const float* __restrict__ attn_w,
                                                   const float* __restrict__ attn_b,
                                                   const int* __restrict__ lengths,
                                                   float* __restrict__ ctx) {
    int b = blockIdx.x;
    int tid = threadIdx.x;
    int len = lengths[b];
    __shared__ __align__(16) float wl[256];
    __shared__ float pl[256];
    __shared__ float red[256];
    wl[tid] = attn_w[tid];
    __syncthreads();
    float sc = -3.0e38f;
    if (tid < len) {
        const float4* rf = (const float4*)(hf + ((size_t)b * TT + tid) * HH);
        const float4* rb = (const float4*)(hb + ((size_t)b * TT + tid) * HH);
        const float4* w4 = (const float4*)wl;
        float s = attn_b[0];
        for (int k4 = 0; k4 < 32; ++k4) {
            float4 a = rf[k4], ww = w4[k4];
            s += a.x * ww.x + a.y * ww.y + a.z * ww.z + a.w * ww.w;
        }
        for (int k4 = 0; k4 < 32; ++k4) {
            float4 a = rb[k4], ww = w4[32 + k4];
            s += a.x * ww.x + a.y * ww.y + a.z * ww.z + a.w * ww.w;
        }
        sc = s;
    }
    red[tid] = sc;
    __syncthreads();
    for (int off = 128; off > 0; off >>= 1) {
        if (tid < off) red[tid] = fmaxf(red[tid], red[tid + off]);
        __syncthreads();
    }
    float mx = red[0];
    __syncthreads();
    float e = (tid < len) ? __expf(sc - mx) : 0.0f;
    red[tid] = e;
    __syncthreads();
    for (int off = 128; off > 0; off >>= 1) {
        if (tid < off) red[tid] += red[tid + off];
        __syncthreads();
    }
    float inv = 1.0f / red[0];
    pl[tid] = e * inv;
    __syncthreads();
    float acc = 0.0f;
    const float* basep = (tid < HH) ? (hf + (size_t)b * TT * HH + tid)
                                    : (hb + (size_t)b * TT * HH + (tid - HH));
#pragma unroll 4
    for (int t = 0; t < len; ++t) acc += pl[t] * basep[(size_t)t * HH];
    ctx[(size_t)b * 256 + tid] = acc;
}

// ---------------- final FC: [64,256] @ [256,N] + b ----------------
__global__ __launch_bounds__(256) void fc_kernel(const float* __restrict__ ctx,
                                                 const float* __restrict__ fc_w,
                                                 const float* __restrict__ fc_b,
                                                 float* __restrict__ out) {
    __shared__ __align__(16) float cl[64][256];
    for (int i = threadIdx.x; i < 64 * 256 / 4; i += 256)
        ((float4*)cl)[i] = ((const float4*)ctx)[i];
    __syncthreads();
    int nb = threadIdx.x & 63;
    int bq = threadIdx.x >> 6;
    int n = blockIdx.x * 64 + nb;
    if (n >= NN) return;
    float acc[16];
#pragma unroll
    for (int i = 0; i < 16; ++i) acc[i] = 0.0f;
#pragma unroll 2
    for (int k4 = 0; k4 < 64; ++k4) {
        int k = k4 * 4;
        float w0 = fc_w[(size_t)k * NN + n];
        float w1 = fc_w[(size_t)(k + 1) * NN + n];
        float w2 = fc_w[(size_t)(k + 2) * NN + n];
        float w3 = fc_w[(size_t)(k + 3) * NN + n];
#pragma unroll
        for (int i = 0; i < 16; ++i) {
            float4 cv = *(const float4*)&cl[bq * 16 + i][k];
            acc[i] += cv.x * w0 + cv.y * w1 + cv.z * w2 + cv.w * w3;
        }
    }
    float fb = fc_b[n];
#pragma unroll
    for (int i = 0; i < 16; ++i)
        out[(size_t)(bq * 16 + i) * NN + n] = acc[i] + fb;
}

// ---------------- host launcher ----------------
extern "C" void kernel_launch(void* const* d_in, const int* in_sizes, int n_in,
                              void* d_out, int out_size, void* d_ws, size_t ws_size,
                              hipStream_t stream) {
    const float* x_coords   = (const float*)d_in[0];
    const float* temporal   = (const float*)d_in[1];
    const int*   edge_index = (const int*)d_in[2];
    const float* edge_w     = (const float*)d_in[3];
    const int*   seq        = (const int*)d_in[4];
    const int*   lengths    = (const int*)d_in[5];
    const float* node_emb   = (const float*)d_in[6];
    const float* gcn1_w     = (const float*)d_in[7];
    const float* gcn1_b     = (const float*)d_in[8];
    const float* gcn2_w     = (const float*)d_in[9];
    const float* gcn2_b     = (const float*)d_in[10];
    const float* w_ih_f     = (const float*)d_in[11];
    const float* w_hh_f     = (const float*)d_in[12];
    const float* b_ih_f     = (const float*)d_in[13];
    const float* b_hh_f     = (const float*)d_in[14];
    const float* w_ih_b     = (const float*)d_in[15];
    const float* w_hh_b     = (const float*)d_in[16];
    const float* b_ih_b     = (const float*)d_in[17];
    const float* b_hh_b     = (const float*)d_in[18];
    const float* attn_w     = (const float*)d_in[19];
    const float* attn_b     = (const float*)d_in[20];
    const float* fc_w       = (const float*)d_in[21];
    const float* fc_b       = (const float*)d_in[22];
    float* out = (float*)d_out;

    char* base = (char*)d_ws;
    size_t off = 0;
    auto alloc = [&](size_t nbytes) -> void* {
        void* p = base + off;
        off = (off + nbytes + 255) & ~(size_t)255;
        return p;
    };
    int*   cnt     = (int*)alloc((size_t)2 * NN * 4);  // cnt + degw contiguous (one memset)
    float* degw    = (float*)(cnt + NN);
    float* dinv    = (float*)alloc((size_t)NN * 4);
    int*   rs      = (int*)alloc(((size_t)NN + 1) * 4);
    int*   cursor  = (int*)alloc((size_t)NN * 4);
    int*   partials= (int*)alloc(64 * 4);
    int*   ssrc    = (int*)alloc((size_t)NE * 4);
    float* sw      = (float*)alloc((size_t)NE * 4);
    float* h1      = (float*)alloc((size_t)NN * GH * 4);
    float* z1      = (float*)alloc((size_t)NN * GH * 4);
    float* a2      = h1;  // h1 dead after agg1
    float* z2      = (float*)alloc((size_t)NN * EMB * 4);
    float* se      = (float*)alloc((size_t)BB * TT * EMB * 4);
    float* xpf     = (float*)alloc((size_t)TT * BB * G4 * 4);
    float* xpb     = (float*)alloc((size_t)TT * BB * G4 * 4);
    float* hfo     = (float*)alloc((size_t)BB * TT * HH * 4);
    float* hbo     = (float*)alloc((size_t)BB * TT * HH * 4);
    float* ctx     = (float*)alloc((size_t)BB * 256 * 4);
    (void)ws_size; (void)in_sizes; (void)n_in; (void)out_size;

    hipMemsetAsync(cnt, 0, (size_t)2 * NN * 4, stream);

    hist_kernel<<<(NE + 255) / 256, 256, 0, stream>>>(edge_index, edge_w, cnt, degw);
    dinv_kernel<<<(NN + 255) / 256, 256, 0, stream>>>(degw, dinv);
    const int nblk = (NN + 1023) / 1024;  // 49
    scan1_kernel<<<nblk, 1024, 0, stream>>>(cnt, rs, partials);
    scan2_kernel<<<1, 64, 0, stream>>>(partials, nblk);
    scan3_kernel<<<nblk, 1024, 0, stream>>>(partials, rs, cursor);
    fill_kernel<<<(NE + 255) / 256, 256, 0, stream>>>(edge_index, edge_w, dinv, cursor, ssrc, sw);

    gemm1_kernel<<<(NN + 255) / 256, 256, 0, stream>>>(x_coords, temporal, node_emb, gcn1_w, h1);
    agg_kernel<<<(NN + 3) / 4, 256, 0, stream>>>(h1, rs, ssrc, sw, dinv, gcn1_b, 1, z1);
    agg_kernel<<<(NN + 3) / 4, 256, 0, stream>>>(z1, rs, ssrc, sw, dinv, (const float*)nullptr, 0, a2);
    gemm2_kernel<<<dim3((NN + 255) / 256, 2), 256, 0, stream>>>(a2, gcn2_w, gcn2_b, z2);

    gather_kernel<<<(BB * TT * 32 + 255) / 256, 256, 0, stream>>>(seq, z2, se);
    pregemm_kernel<<<dim3(TT * BB / 256, 8, 2), 256, 0, stream>>>(
        se, w_ih_f, w_ih_b, b_ih_f, b_hh_f, b_ih_b, b_hh_b, lengths, xpf, xpb);
    lstm_kernel<<<BB * 2, 512, 0, stream>>>(xpf, xpb, w_hh_f, w_hh_b, lengths, hfo, hbo);
    attn_kernel<<<BB, 256, 0, stream>>>(hfo, hbo, attn_w, attn_b, lengths, ctx);
    fc_kernel<<<(NN + 63) / 64, 256, 0, stream>>>(ctx, fc_w, fc_b, out);
}